// Round 2
// baseline (225.227 us; speedup 1.0000x reference)
//
#include <hip/hip_runtime.h>
#include <math.h>

// B=1048576 rows, IN=25, H=64, OUT=6.
// Algebra: h0==0 => gh=b_hh (w_hh matmul gone); pre+ih fuse into one 192x25 GEMM.
// R1 lesson: LDS broadcast reads of the weight table were the bottleneck
// (~24 ds_read_b128/k-iter ~= 590k LDS-pipe cycles ~= the whole 240us).
// R2: weights read via wave-UNIFORM global loads -> compiler emits s_load into
// SGPRs (scalar K$); gate FMAs are v_fma_f32 v,s,v. LDS pipe usage -> 0.
//
// Table layout per hidden unit k (stride 112 floats, 16-float aligned groups):
//   [0..24]   Wr fused weights    [32..56] Wz    [64..88] Wn
//   [96..101] ow[o]=out_w[o][k]
//   [104]=fb_r(+b_hh_r) [105]=fb_z(+b_hh_z) [106]=fb_n [107]=b_hh_n

#define IN   25
#define HID  64
#define NOUT 6
#define KST  112
#define BLK  256
#define RPT  2
#define LOG2E 1.4426950408889634f

__device__ __forceinline__ float rcpf_(float x) { return __builtin_amdgcn_rcpf(x); }
__device__ __forceinline__ float sig_(float a) {
    return rcpf_(1.0f + exp2f(-a * LOG2E));
}
__device__ __forceinline__ float tanh_(float a) {
    return fmaf(-2.0f, rcpf_(exp2f(a * (2.0f * LOG2E)) + 1.0f), 1.0f);
}

__global__ void prep_kernel(const float* __restrict__ pre_w, const float* __restrict__ pre_b,
                            const float* __restrict__ w_ih, const float* __restrict__ b_ih,
                            const float* __restrict__ b_hh, const float* __restrict__ out_w,
                            float* __restrict__ tab) {
    int k = blockIdx.x;   // 0..63 hidden unit
    int t = threadIdx.x;  // 0..127
    float* tb = tab + k * KST;
    if (t < 75) {                       // fused W[g*64+k][c] = sum_j w_ih[g*64+k][j]*pre_w[j][c]
        int g = t / 25, c = t % 25;
        const float* wrow = w_ih + (g * HID + k) * HID;
        float s = 0.0f;
        for (int j = 0; j < HID; ++j) s = fmaf(wrow[j], pre_w[j * IN + c], s);
        tb[g * 32 + c] = s;
    } else if (t < 78) {                // fused biases
        int g = t - 75;
        const float* wrow = w_ih + (g * HID + k) * HID;
        float s = 0.0f;
        for (int j = 0; j < HID; ++j) s = fmaf(wrow[j], pre_b[j], s);
        s += b_ih[g * HID + k];
        if (g < 2) s += b_hh[g * HID + k];   // r,z: h-bias folds in (h0==0)
        tb[104 + g] = s;
    } else if (t == 78) {
        tb[107] = b_hh[2 * HID + k];         // b_hh_n (scaled by r later)
    } else if (t < 85) {
        int o = t - 79;
        tb[96 + o] = out_w[o * HID + k];     // transposed head column
    }
}

__device__ __forceinline__ void softmax_store(const float (&lg)[NOUT], float* dst) {
    float m = lg[0];
#pragma unroll
    for (int o = 1; o < NOUT; ++o) m = fmaxf(m, lg[o]);
    float e[NOUT];
    float s = 0.0f;
#pragma unroll
    for (int o = 0; o < NOUT; ++o) { e[o] = exp2f((lg[o] - m) * LOG2E); s += e[o]; }
    float is = rcpf_(s);
    float2* p2 = (float2*)dst;   // row*24 B -> 8B aligned
    p2[0] = make_float2(e[0] * is, e[1] * is);
    p2[1] = make_float2(e[2] * is, e[3] * is);
    p2[2] = make_float2(e[4] * is, e[5] * is);
}

__global__ __launch_bounds__(BLK, 4) void gru_head_kernel(const float* __restrict__ x,
                                                          const float* __restrict__ tab,
                                                          const float* __restrict__ out_b,
                                                          float* __restrict__ out,
                                                          int nrows) {
    const int half = gridDim.x * BLK;
    const int gid = blockIdx.x * BLK + threadIdx.x;
    const int row0 = gid;
    const int row1 = gid + half;
    const bool v0 = row0 < nrows, v1 = row1 < nrows;

    float xv0[IN], xv1[IN];
#pragma unroll
    for (int c = 0; c < IN; ++c) {
        xv0[c] = v0 ? x[(size_t)row0 * IN + c] : 0.0f;
        xv1[c] = v1 ? x[(size_t)row1 * IN + c] : 0.0f;
    }
    float lg0[NOUT], lg1[NOUT];
#pragma unroll
    for (int o = 0; o < NOUT; ++o) { float b = out_b[o]; lg0[o] = b; lg1[o] = b; }

#pragma unroll 1
    for (int k = 0; k < HID; ++k) {
        // all addresses below depend only on k -> wave-uniform -> s_load / SGPR
        const float* __restrict__ p = tab + k * KST;
        float fr = p[104], fz = p[105], fn = p[106], bn = p[107];
        float ar0 = fr, az0 = fz, an0 = fn;
        float ar1 = fr, az1 = fz, an1 = fn;
#pragma unroll
        for (int c = 0; c < IN; ++c) {
            float wr = p[c], wz = p[32 + c], wn = p[64 + c];
            ar0 = fmaf(wr, xv0[c], ar0); ar1 = fmaf(wr, xv1[c], ar1);
            az0 = fmaf(wz, xv0[c], az0); az1 = fmaf(wz, xv1[c], az1);
            an0 = fmaf(wn, xv0[c], an0); an1 = fmaf(wn, xv1[c], an1);
        }
        float r0 = sig_(ar0), r1 = sig_(ar1);
        float z0 = sig_(az0), z1 = sig_(az1);
        float n0 = tanh_(fmaf(r0, bn, an0));
        float n1 = tanh_(fmaf(r1, bn, an1));
        float h0 = fmaf(-z0, n0, n0);   // (1-z)*n, h_prev==0
        float h1 = fmaf(-z1, n1, n1);

        float o0 = p[96], o1 = p[97], o2 = p[98], o3 = p[99], o4 = p[100], o5 = p[101];
        lg0[0] = fmaf(h0, o0, lg0[0]); lg1[0] = fmaf(h1, o0, lg1[0]);
        lg0[1] = fmaf(h0, o1, lg0[1]); lg1[1] = fmaf(h1, o1, lg1[1]);
        lg0[2] = fmaf(h0, o2, lg0[2]); lg1[2] = fmaf(h1, o2, lg1[2]);
        lg0[3] = fmaf(h0, o3, lg0[3]); lg1[3] = fmaf(h1, o3, lg1[3]);
        lg0[4] = fmaf(h0, o4, lg0[4]); lg1[4] = fmaf(h1, o4, lg1[4]);
        lg0[5] = fmaf(h0, o5, lg0[5]); lg1[5] = fmaf(h1, o5, lg1[5]);
    }

    if (v0) softmax_store(lg0, out + (size_t)row0 * NOUT);
    if (v1) softmax_store(lg1, out + (size_t)row1 * NOUT);
}

extern "C" void kernel_launch(void* const* d_in, const int* in_sizes, int n_in,
                              void* d_out, int out_size, void* d_ws, size_t ws_size,
                              hipStream_t stream) {
    const float* x     = (const float*)d_in[0];
    const float* pre_w = (const float*)d_in[1];
    const float* pre_b = (const float*)d_in[2];
    const float* w_ih  = (const float*)d_in[3];
    // d_in[4] = w_hh unused (h0==0 -> gh=b_hh exactly)
    const float* b_ih  = (const float*)d_in[5];
    const float* b_hh  = (const float*)d_in[6];
    const float* out_w = (const float*)d_in[7];
    const float* out_b = (const float*)d_in[8];
    // d_in[9] = h0 all-zeros, unused

    float* tab = (float*)d_ws;   // 64*112*4 = 28672 B
    const int nrows = in_sizes[0] / IN;
    const int grid = (nrows + BLK * RPT - 1) / (BLK * RPT);

    prep_kernel<<<HID, 128, 0, stream>>>(pre_w, pre_b, w_ih, b_ih, b_hh, out_w, tab);
    gru_head_kernel<<<grid, BLK, 0, stream>>>(x, tab, out_b, (float*)d_out, nrows);
}

// Round 3
// 224.650 us; speedup vs baseline: 1.0026x; 1.0026x over previous
//
#include <hip/hip_runtime.h>
#include <math.h>

// B=1048576 rows, IN=25, H=64, OUT=6.
// Algebra: h0==0 => gh=b_hh (w_hh matmul gone); pre+ih fuse into one 192x25 GEMM.
// R1/R2 lesson: VGPR_Count=40 exposed that the compiler REMATERIALIZED the x
// loads inside the k-loop (legal for const __restrict__) -> 64x re-read of x
// through L1/L2 (~27 TB/s, L2-bound at ~245us) in both rounds. The weight path
// (LDS vs s_load) was never the limiter.
// R3: pin the 50 x-values in VGPRs via empty asm keep-alive (non-remat result).
// Weights stay wave-uniform s_loads (scalar K$), gate FMAs are v_fma v,s,v.
//
// Table layout per hidden unit k (stride 112 floats, 16-float aligned groups):
//   [0..24]   Wr fused weights    [32..56] Wz    [64..88] Wn
//   [96..101] ow[o]=out_w[o][k]
//   [104]=fb_r(+b_hh_r) [105]=fb_z(+b_hh_z) [106]=fb_n [107]=b_hh_n

#define IN   25
#define HID  64
#define NOUT 6
#define KST  112
#define BLK  256
#define RPT  2
#define LOG2E 1.4426950408889634f

__device__ __forceinline__ float rcpf_(float x) { return __builtin_amdgcn_rcpf(x); }
__device__ __forceinline__ float sig_(float a) {
    return rcpf_(1.0f + exp2f(-a * LOG2E));
}
__device__ __forceinline__ float tanh_(float a) {
    return fmaf(-2.0f, rcpf_(exp2f(a * (2.0f * LOG2E)) + 1.0f), 1.0f);
}

__global__ void prep_kernel(const float* __restrict__ pre_w, const float* __restrict__ pre_b,
                            const float* __restrict__ w_ih, const float* __restrict__ b_ih,
                            const float* __restrict__ b_hh, const float* __restrict__ out_w,
                            float* __restrict__ tab) {
    int k = blockIdx.x;   // 0..63 hidden unit
    int t = threadIdx.x;  // 0..127
    float* tb = tab + k * KST;
    if (t < 75) {                       // fused W[g*64+k][c] = sum_j w_ih[g*64+k][j]*pre_w[j][c]
        int g = t / 25, c = t % 25;
        const float* wrow = w_ih + (g * HID + k) * HID;
        float s = 0.0f;
        for (int j = 0; j < HID; ++j) s = fmaf(wrow[j], pre_w[j * IN + c], s);
        tb[g * 32 + c] = s;
    } else if (t < 78) {                // fused biases
        int g = t - 75;
        const float* wrow = w_ih + (g * HID + k) * HID;
        float s = 0.0f;
        for (int j = 0; j < HID; ++j) s = fmaf(wrow[j], pre_b[j], s);
        s += b_ih[g * HID + k];
        if (g < 2) s += b_hh[g * HID + k];   // r,z: h-bias folds in (h0==0)
        tb[104 + g] = s;
    } else if (t == 78) {
        tb[107] = b_hh[2 * HID + k];         // b_hh_n (scaled by r later)
    } else if (t < 85) {
        int o = t - 79;
        tb[96 + o] = out_w[o * HID + k];     // transposed head column
    }
}

__device__ __forceinline__ void softmax_store(const float (&lg)[NOUT], float* dst) {
    float m = lg[0];
#pragma unroll
    for (int o = 1; o < NOUT; ++o) m = fmaxf(m, lg[o]);
    float e[NOUT];
    float s = 0.0f;
#pragma unroll
    for (int o = 0; o < NOUT; ++o) { e[o] = exp2f((lg[o] - m) * LOG2E); s += e[o]; }
    float is = rcpf_(s);
    float2* p2 = (float2*)dst;   // row*24 B -> 8B aligned
    p2[0] = make_float2(e[0] * is, e[1] * is);
    p2[1] = make_float2(e[2] * is, e[3] * is);
    p2[2] = make_float2(e[4] * is, e[5] * is);
}

__global__ __launch_bounds__(BLK, 4) void gru_head_kernel(const float* __restrict__ x,
                                                          const float* __restrict__ tab,
                                                          const float* __restrict__ out_b,
                                                          float* __restrict__ out,
                                                          int nrows) {
    const int half = gridDim.x * BLK;
    const int gid = blockIdx.x * BLK + threadIdx.x;
    const int row0 = gid;
    const int row1 = gid + half;
    const bool v0 = row0 < nrows, v1 = row1 < nrows;

    float xv0[IN], xv1[IN];
#pragma unroll
    for (int c = 0; c < IN; ++c) {
        xv0[c] = v0 ? x[(size_t)row0 * IN + c] : 0.0f;
        xv1[c] = v1 ? x[(size_t)row1 * IN + c] : 0.0f;
    }
    // Pin x in VGPRs: asm result is not rematerializable, so the compiler must
    // keep all 50 values live instead of re-loading from global every k-iter.
#pragma unroll
    for (int c = 0; c < IN; ++c) {
        asm volatile("" : "+v"(xv0[c]), "+v"(xv1[c]));
    }

    float lg0[NOUT], lg1[NOUT];
#pragma unroll
    for (int o = 0; o < NOUT; ++o) { float b = out_b[o]; lg0[o] = b; lg1[o] = b; }

#pragma unroll 1
    for (int k = 0; k < HID; ++k) {
        // addresses depend only on k -> wave-uniform -> s_load / SGPR operands
        const float* __restrict__ p = tab + k * KST;
        float fr = p[104], fz = p[105], fn = p[106], bn = p[107];
        float ar0 = fr, az0 = fz, an0 = fn;
        float ar1 = fr, az1 = fz, an1 = fn;
#pragma unroll
        for (int c = 0; c < IN; ++c) {
            float wr = p[c], wz = p[32 + c], wn = p[64 + c];
            ar0 = fmaf(wr, xv0[c], ar0); ar1 = fmaf(wr, xv1[c], ar1);
            az0 = fmaf(wz, xv0[c], az0); az1 = fmaf(wz, xv1[c], az1);
            an0 = fmaf(wn, xv0[c], an0); an1 = fmaf(wn, xv1[c], an1);
        }
        float r0 = sig_(ar0), r1 = sig_(ar1);
        float z0 = sig_(az0), z1 = sig_(az1);
        float n0 = tanh_(fmaf(r0, bn, an0));
        float n1 = tanh_(fmaf(r1, bn, an1));
        float h0 = fmaf(-z0, n0, n0);   // (1-z)*n, h_prev==0
        float h1 = fmaf(-z1, n1, n1);

        float o0 = p[96], o1 = p[97], o2 = p[98], o3 = p[99], o4 = p[100], o5 = p[101];
        lg0[0] = fmaf(h0, o0, lg0[0]); lg1[0] = fmaf(h1, o0, lg1[0]);
        lg0[1] = fmaf(h0, o1, lg0[1]); lg1[1] = fmaf(h1, o1, lg1[1]);
        lg0[2] = fmaf(h0, o2, lg0[2]); lg1[2] = fmaf(h1, o2, lg1[2]);
        lg0[3] = fmaf(h0, o3, lg0[3]); lg1[3] = fmaf(h1, o3, lg1[3]);
        lg0[4] = fmaf(h0, o4, lg0[4]); lg1[4] = fmaf(h1, o4, lg1[4]);
        lg0[5] = fmaf(h0, o5, lg0[5]); lg1[5] = fmaf(h1, o5, lg1[5]);
    }

    if (v0) softmax_store(lg0, out + (size_t)row0 * NOUT);
    if (v1) softmax_store(lg1, out + (size_t)row1 * NOUT);
}

extern "C" void kernel_launch(void* const* d_in, const int* in_sizes, int n_in,
                              void* d_out, int out_size, void* d_ws, size_t ws_size,
                              hipStream_t stream) {
    const float* x     = (const float*)d_in[0];
    const float* pre_w = (const float*)d_in[1];
    const float* pre_b = (const float*)d_in[2];
    const float* w_ih  = (const float*)d_in[3];
    // d_in[4] = w_hh unused (h0==0 -> gh=b_hh exactly)
    const float* b_ih  = (const float*)d_in[5];
    const float* b_hh  = (const float*)d_in[6];
    const float* out_w = (const float*)d_in[7];
    const float* out_b = (const float*)d_in[8];
    // d_in[9] = h0 all-zeros, unused

    float* tab = (float*)d_ws;   // 64*112*4 = 28672 B
    const int nrows = in_sizes[0] / IN;
    const int grid = (nrows + BLK * RPT - 1) / (BLK * RPT);

    prep_kernel<<<HID, 128, 0, stream>>>(pre_w, pre_b, w_ih, b_ih, b_hh, out_w, tab);
    gru_head_kernel<<<grid, BLK, 0, stream>>>(x, tab, out_b, (float*)d_out, nrows);
}

// Round 4
// 211.205 us; speedup vs baseline: 1.0664x; 1.0637x over previous
//
#include <hip/hip_runtime.h>
#include <math.h>

// B=1048576 rows, IN=25, H=64, OUT=6.
// Algebra: h0==0 => gh=b_hh (w_hh matmul gone); pre+ih fuse into one 192x25 GEMM.
// R1-R3 lesson: at 2 rows/thread the kernel needs ~90 VGPR but hipcc's
// occupancy heuristic targets 8 waves/SIMD (<=64 VGPR), so it re-fetched x
// from L1/L2 every k-iter (~6.7 GB/dispatch, ~27 TB/s = L2-bound at ~247us).
// VGPR_Count=40 was the tell. (VALUBusy ~86% is gfx94x-formula-inflated 2x.)
// R4: 1 row/thread -> natural need ~50 VGPR fits UNDER the 64-VGPR/8-wave
// target, so x stays in registers without fighting the heuristic.
//
// Table layout per hidden unit k (stride 112 floats, 16-float aligned groups):
//   [0..24]   Wr fused weights    [32..56] Wz    [64..88] Wn
//   [96..101] ow[o]=out_w[o][k]
//   [104]=fb_r(+b_hh_r) [105]=fb_z(+b_hh_z) [106]=fb_n [107]=b_hh_n

#define IN   25
#define HID  64
#define NOUT 6
#define KST  112
#define BLK  256
#define LOG2E 1.4426950408889634f

__device__ __forceinline__ float rcpf_(float x) { return __builtin_amdgcn_rcpf(x); }
__device__ __forceinline__ float sig_(float a) {
    return rcpf_(1.0f + exp2f(-a * LOG2E));
}
__device__ __forceinline__ float tanh_(float a) {
    return fmaf(-2.0f, rcpf_(exp2f(a * (2.0f * LOG2E)) + 1.0f), 1.0f);
}

__global__ void prep_kernel(const float* __restrict__ pre_w, const float* __restrict__ pre_b,
                            const float* __restrict__ w_ih, const float* __restrict__ b_ih,
                            const float* __restrict__ b_hh, const float* __restrict__ out_w,
                            float* __restrict__ tab) {
    int k = blockIdx.x;   // 0..63 hidden unit
    int t = threadIdx.x;  // 0..127
    float* tb = tab + k * KST;
    if (t < 75) {                       // fused W[g*64+k][c] = sum_j w_ih[g*64+k][j]*pre_w[j][c]
        int g = t / 25, c = t % 25;
        const float* wrow = w_ih + (g * HID + k) * HID;
        float s = 0.0f;
        for (int j = 0; j < HID; ++j) s = fmaf(wrow[j], pre_w[j * IN + c], s);
        tb[g * 32 + c] = s;
    } else if (t < 78) {                // fused biases
        int g = t - 75;
        const float* wrow = w_ih + (g * HID + k) * HID;
        float s = 0.0f;
        for (int j = 0; j < HID; ++j) s = fmaf(wrow[j], pre_b[j], s);
        s += b_ih[g * HID + k];
        if (g < 2) s += b_hh[g * HID + k];   // r,z: h-bias folds in (h0==0)
        tb[104 + g] = s;
    } else if (t == 78) {
        tb[107] = b_hh[2 * HID + k];         // b_hh_n (scaled by r later)
    } else if (t < 85) {
        int o = t - 79;
        tb[96 + o] = out_w[o * HID + k];     // transposed head column
    }
}

__device__ __forceinline__ void softmax_store(const float (&lg)[NOUT], float* dst) {
    float m = lg[0];
#pragma unroll
    for (int o = 1; o < NOUT; ++o) m = fmaxf(m, lg[o]);
    float e[NOUT];
    float s = 0.0f;
#pragma unroll
    for (int o = 0; o < NOUT; ++o) { e[o] = exp2f((lg[o] - m) * LOG2E); s += e[o]; }
    float is = rcpf_(s);
    float2* p2 = (float2*)dst;   // row*24 B -> 8B aligned
    p2[0] = make_float2(e[0] * is, e[1] * is);
    p2[1] = make_float2(e[2] * is, e[3] * is);
    p2[2] = make_float2(e[4] * is, e[5] * is);
}

__global__ __launch_bounds__(BLK, 4) void gru_head_kernel(const float* __restrict__ x,
                                                          const float* __restrict__ tab,
                                                          const float* __restrict__ out_b,
                                                          float* __restrict__ out,
                                                          int nrows) {
    const int row = blockIdx.x * BLK + threadIdx.x;
    const bool valid = row < nrows;
    const float* __restrict__ xr = x + (size_t)row * IN;

    float xv[IN];
#pragma unroll
    for (int c = 0; c < IN; ++c) xv[c] = valid ? xr[c] : 0.0f;
    // keep-alive: forbid remat of the x loads inside the k-loop
#pragma unroll
    for (int c = 0; c < IN; ++c) asm volatile("" : "+v"(xv[c]));

    float lg[NOUT];
#pragma unroll
    for (int o = 0; o < NOUT; ++o) lg[o] = out_b[o];

#pragma unroll 2
    for (int k = 0; k < HID; ++k) {
        // addresses depend only on k -> wave-uniform -> s_load / SGPR operands
        const float* __restrict__ p = tab + k * KST;
        float ar = p[104], az = p[105], an = p[106];
        float bn = p[107];
#pragma unroll
        for (int c = 0; c < IN; ++c) {
            ar = fmaf(p[c],      xv[c], ar);
            az = fmaf(p[32 + c], xv[c], az);
            an = fmaf(p[64 + c], xv[c], an);
        }
        float r = sig_(ar);
        float z = sig_(az);
        float n = tanh_(fmaf(r, bn, an));
        float h = fmaf(-z, n, n);   // (1-z)*n, h_prev==0

        lg[0] = fmaf(h, p[96],  lg[0]);
        lg[1] = fmaf(h, p[97],  lg[1]);
        lg[2] = fmaf(h, p[98],  lg[2]);
        lg[3] = fmaf(h, p[99],  lg[3]);
        lg[4] = fmaf(h, p[100], lg[4]);
        lg[5] = fmaf(h, p[101], lg[5]);
    }

    if (valid) softmax_store(lg, out + (size_t)row * NOUT);
}

extern "C" void kernel_launch(void* const* d_in, const int* in_sizes, int n_in,
                              void* d_out, int out_size, void* d_ws, size_t ws_size,
                              hipStream_t stream) {
    const float* x     = (const float*)d_in[0];
    const float* pre_w = (const float*)d_in[1];
    const float* pre_b = (const float*)d_in[2];
    const float* w_ih  = (const float*)d_in[3];
    // d_in[4] = w_hh unused (h0==0 -> gh=b_hh exactly)
    const float* b_ih  = (const float*)d_in[5];
    const float* b_hh  = (const float*)d_in[6];
    const float* out_w = (const float*)d_in[7];
    const float* out_b = (const float*)d_in[8];
    // d_in[9] = h0 all-zeros, unused

    float* tab = (float*)d_ws;   // 64*112*4 = 28672 B
    const int nrows = in_sizes[0] / IN;
    const int grid = (nrows + BLK - 1) / BLK;

    prep_kernel<<<HID, 128, 0, stream>>>(pre_w, pre_b, w_ih, b_ih, b_hh, out_w, tab);
    gru_head_kernel<<<grid, BLK, 0, stream>>>(x, tab, out_b, (float*)d_out, nrows);
}

// Round 6
// 117.524 us; speedup vs baseline: 1.9164x; 1.7971x over previous
//
#include <hip/hip_runtime.h>

// B=1048576, IN=25, H=64, OUT=6.  h0==0 => gh=b_hh; pre+ih fuse into W[192][26].
// R1-R4: hipcc refuses to keep a ~50-VGPR x working set live -> L2-refetch-bound
// ~230us on the scalar path. R5: MFMA formulation (16 rows per wave-iter).
// R5 BUG: rpw used 64 "waves/block" instead of 4 -> only 65536/1048576 rows
// written (absmax 0.277 = softmax-vs-zeros). R6 = R5 with rpw fixed (=32).
//   gates: D[u][b] = W(192x32,bf16) * x^T(32x16, split-bf16 xh+xl) : 24 mfma_16x16x32_bf16
//          bias via K-slots 25,26 (x=1, W cols = bias hi/lo split)
//   activations: per-lane (r,z,n share (u,b) coords; C layout col=l&15,row=(l>>4)*4+reg)
//   head: D[o][b] = ow(16x64,bf16) * h(64x16,bf16) : 2 mfma; h C-layout -> B-frag via
//         in-wave LDS bounce (ds_write_b64 x4 + ds_read_b128 x2, padded rows)
//   softmax in-lane after ds_swizzle xor16; store by lanes 0..15.
// Weights live in VGPR frags once (asm-pinned); row loop has zero weight loads.

#define IN   25
#define HID  64
#define NOUT 6
#define LOG2E 1.4426950408889634f
#define NB   512   // blocks
#define WPB  4     // waves per block (256 threads)

typedef __attribute__((ext_vector_type(8))) short bf16x8_t;
typedef __attribute__((ext_vector_type(4))) float f32x4_t;

__device__ __forceinline__ float rcpf_(float x) { return __builtin_amdgcn_rcpf(x); }
__device__ __forceinline__ float sig_(float a) {
    return rcpf_(1.0f + exp2f(-a * LOG2E));
}
__device__ __forceinline__ float tanh_(float a) {
    return fmaf(-2.0f, rcpf_(exp2f(a * (2.0f * LOG2E)) + 1.0f), 1.0f);
}
__device__ __forceinline__ unsigned rne_bf16(float f) {
    unsigned u = __float_as_uint(f);
    u += 0x7fffu + ((u >> 16) & 1u);
    return u >> 16;                       // low 16 bits = bf16
}
__device__ __forceinline__ float bf16_f(unsigned h) { return __uint_as_float(h << 16); }

// ---- prep: Wm[192][32] fp32: fused weights, bias split in cols 25/26, 27..31 = 0
__global__ void prep_kernel(const float* __restrict__ pre_w, const float* __restrict__ pre_b,
                            const float* __restrict__ w_ih, const float* __restrict__ b_ih,
                            const float* __restrict__ b_hh, float* __restrict__ wm) {
    int u = blockIdx.x;    // 0..191 (gate-unit, torch order r|z|n)
    int c = threadIdx.x;   // 0..31
    const float* wrow = w_ih + u * HID;
    float v = 0.0f;
    if (c < IN) {                          // fused weight
        float s = 0.0f;
        for (int j = 0; j < HID; ++j) s = fmaf(wrow[j], pre_w[j * IN + c], s);
        v = s;
    } else if (c == IN || c == IN + 1) {   // bias (hi via later RNE in col25, lo resid col26)
        float s = 0.0f;
        for (int j = 0; j < HID; ++j) s = fmaf(wrow[j], pre_b[j], s);
        s += b_ih[u];
        if (u < 2 * HID) s += b_hh[u];     // r,z gates: h-bias folds in (h0==0)
        v = (c == IN) ? s : (s - bf16_f(rne_bf16(s)));
    }
    wm[u * 32 + c] = v;
}

__global__ __launch_bounds__(256, 2) void gru_head_mfma(const float* __restrict__ x,
                                                        const float* __restrict__ wm,
                                                        const float* __restrict__ b_hh,
                                                        const float* __restrict__ out_w,
                                                        const float* __restrict__ out_b,
                                                        float* __restrict__ out,
                                                        int nrows, int rpw) {
    __shared__ int4 lds4[4 * 144];         // 4 waves * 16 rows * 36 dwords (pad 36 vs 32)

    const int lane = threadIdx.x & 63;
    const int widx = threadIdx.x >> 6;     // wave in block 0..3
    const int b    = lane & 15;            // batch row within 16-tile / frag col
    const int g4   = lane >> 4;            // k-group 0..3
    const int wave_g = blockIdx.x * WPB + widx;

    // ---- A-frags: W tiles (once). A[m=u_local][k=c]: m=l&15, k=g4*8+j.
    bf16x8_t wf[12];
#pragma unroll
    for (int t = 0; t < 12; ++t) {
        const float* p = wm + (t * 16 + b) * 32 + g4 * 8;
        f32x4_t a = *(const f32x4_t*)p;
        f32x4_t c4 = *(const f32x4_t*)(p + 4);
        bf16x8_t f;
        f[0] = (short)rne_bf16(a.x); f[1] = (short)rne_bf16(a.y);
        f[2] = (short)rne_bf16(a.z); f[3] = (short)rne_bf16(a.w);
        f[4] = (short)rne_bf16(c4.x); f[5] = (short)rne_bf16(c4.y);
        f[6] = (short)rne_bf16(c4.z); f[7] = (short)rne_bf16(c4.w);
        wf[t] = f;
    }
    // ---- head A-frags: ow[o][k], o=l&15 (>=6 -> 0), k=g4*8+j+32s  (once)
    bf16x8_t owf[2];
#pragma unroll
    for (int s = 0; s < 2; ++s) {
        bf16x8_t f;
        if (b < NOUT) {
            const float* p = out_w + b * HID + 32 * s + g4 * 8;
            f32x4_t a = *(const f32x4_t*)p;
            f32x4_t c4 = *(const f32x4_t*)(p + 4);
            f[0] = (short)rne_bf16(a.x); f[1] = (short)rne_bf16(a.y);
            f[2] = (short)rne_bf16(a.z); f[3] = (short)rne_bf16(a.w);
            f[4] = (short)rne_bf16(c4.x); f[5] = (short)rne_bf16(c4.y);
            f[6] = (short)rne_bf16(c4.z); f[7] = (short)rne_bf16(c4.w);
        } else {
#pragma unroll
            for (int j = 0; j < 8; ++j) f[j] = 0;
        }
        owf[s] = f;
    }
    // ---- bn (b_hh_n) per-lane: u_h = 16*tt + 4*g4 + reg  (once)
    float bn_[4][4];
#pragma unroll
    for (int tt = 0; tt < 4; ++tt) {
        f32x4_t v = *(const f32x4_t*)(b_hh + 2 * HID + 16 * tt + 4 * g4);
        bn_[tt][0] = v.x; bn_[tt][1] = v.y; bn_[tt][2] = v.z; bn_[tt][3] = v.w;
    }
    // pin everything so it is never rematerialized/refetched in the row loop
#pragma unroll
    for (int t = 0; t < 12; ++t) asm volatile("" : "+v"(wf[t]));
    asm volatile("" : "+v"(owf[0]), "+v"(owf[1]));
#pragma unroll
    for (int tt = 0; tt < 4; ++tt)
        asm volatile("" : "+v"(bn_[tt][0]), "+v"(bn_[tt][1]), "+v"(bn_[tt][2]), "+v"(bn_[tt][3]));

    const float ob0 = out_b[0], ob1 = out_b[1], ob2 = out_b[2],
                ob3 = out_b[3], ob4 = out_b[4], ob5 = out_b[5];
    const f32x4_t Z = {0.0f, 0.0f, 0.0f, 0.0f};

    int2* lds2 = (int2*)lds4;
    const int wb144 = widx * 144, wb288 = widx * 288;

    const int rowstart = wave_g * rpw * 16;
#pragma unroll 1
    for (int it = 0; it < rpw; ++it) {
        const int rowbase = rowstart + it * 16;
        if (rowbase >= nrows) break;
        int row = rowbase + b; if (row >= nrows) row = nrows - 1;
        const float* xrp = x + (size_t)row * IN;

        // ---- B-frags: x row slice k = g4*8 + j, split bf16 (slots 25,26 = 1.0 bias)
        float xr8[8];
        if (g4 < 3) {
            __builtin_memcpy(&xr8[0], xrp + g4 * 8, 16);
            __builtin_memcpy(&xr8[4], xrp + g4 * 8 + 4, 16);
        } else {
            xr8[0] = xrp[24]; xr8[1] = 1.0f; xr8[2] = 1.0f;
            xr8[3] = xr8[4] = xr8[5] = xr8[6] = xr8[7] = 0.0f;
        }
        bf16x8_t xh8, xl8;
#pragma unroll
        for (int j = 0; j < 8; ++j) {
            unsigned h = rne_bf16(xr8[j]);
            xh8[j] = (short)h;
            xl8[j] = (short)rne_bf16(xr8[j] - bf16_f(h));
        }

        // ---- gate GEMM: 12 tiles x 2 mfma (W*xl then W*xh)
        f32x4_t acc[12];
#pragma unroll
        for (int t = 0; t < 12; ++t) {
            f32x4_t a = __builtin_amdgcn_mfma_f32_16x16x32_bf16(wf[t], xl8, Z, 0, 0, 0);
            acc[t] = __builtin_amdgcn_mfma_f32_16x16x32_bf16(wf[t], xh8, a, 0, 0, 0);
        }

        // ---- activations (per-lane) + pack h to bf16 pairs + LDS bounce
#pragma unroll
        for (int tt = 0; tt < 4; ++tt) {
            float h[4];
#pragma unroll
            for (int reg = 0; reg < 4; ++reg) {
                float ar = acc[tt][reg], az = acc[4 + tt][reg], an = acc[8 + tt][reg];
                float r = sig_(ar);
                float z = sig_(az);
                float n = tanh_(fmaf(r, bn_[tt][reg], an));
                h[reg] = fmaf(-z, n, n);          // (1-z)*n, h_prev==0
            }
            int w0 = (int)((rne_bf16(h[1]) << 16) | rne_bf16(h[0]));
            int w1 = (int)((rne_bf16(h[3]) << 16) | rne_bf16(h[2]));
            lds2[wb288 + b * 18 + 4 * tt + g4] = make_int2(w0, w1);
        }
        asm volatile("s_waitcnt lgkmcnt(0)" ::: "memory");
        __builtin_amdgcn_sched_barrier(0);

        // ---- read back h as head B-frags: k = 32s + 8*g4 + j, col = b
        f32x4_t dD;
        {
            union { int4 i4; bf16x8_t h8; } u0, u1;
            int tt0 = (g4 >> 1);
            u0.i4 = lds4[wb144 + 9 * b + 2 * (0 + tt0) + (g4 & 1)];
            u1.i4 = lds4[wb144 + 9 * b + 2 * (2 + tt0) + (g4 & 1)];
            f32x4_t d = __builtin_amdgcn_mfma_f32_16x16x32_bf16(owf[0], u0.h8, Z, 0, 0, 0);
            dD = __builtin_amdgcn_mfma_f32_16x16x32_bf16(owf[1], u1.h8, d, 0, 0, 0);
        }

        // ---- gather 6 logits per b (lane group 0), softmax, store
        float lo4 = __uint_as_float((unsigned)__builtin_amdgcn_ds_swizzle(
                        (int)__float_as_uint(dD[0]), 0x401F));   // from lane^16: o=4
        float lo5 = __uint_as_float((unsigned)__builtin_amdgcn_ds_swizzle(
                        (int)__float_as_uint(dD[1]), 0x401F));   // o=5
        float l0 = dD[0] + ob0, l1 = dD[1] + ob1, l2 = dD[2] + ob2,
              l3 = dD[3] + ob3, l4 = lo4 + ob4, l5 = lo5 + ob5;
        float m = fmaxf(fmaxf(fmaxf(l0, l1), fmaxf(l2, l3)), fmaxf(l4, l5));
        float e0 = exp2f((l0 - m) * LOG2E), e1 = exp2f((l1 - m) * LOG2E),
              e2 = exp2f((l2 - m) * LOG2E), e3 = exp2f((l3 - m) * LOG2E),
              e4 = exp2f((l4 - m) * LOG2E), e5 = exp2f((l5 - m) * LOG2E);
        float is = rcpf_(e0 + e1 + e2 + e3 + e4 + e5);
        if (lane < 16 && rowbase + b < nrows) {
            float* dst = out + (size_t)(rowbase + b) * NOUT;
            float2* p2 = (float2*)dst;
            p2[0] = make_float2(e0 * is, e1 * is);
            p2[1] = make_float2(e2 * is, e3 * is);
            p2[2] = make_float2(e4 * is, e5 * is);
        }
    }
}

extern "C" void kernel_launch(void* const* d_in, const int* in_sizes, int n_in,
                              void* d_out, int out_size, void* d_ws, size_t ws_size,
                              hipStream_t stream) {
    const float* x     = (const float*)d_in[0];
    const float* pre_w = (const float*)d_in[1];
    const float* pre_b = (const float*)d_in[2];
    const float* w_ih  = (const float*)d_in[3];
    // d_in[4] = w_hh unused (h0==0 -> gh=b_hh exactly)
    const float* b_ih  = (const float*)d_in[5];
    const float* b_hh  = (const float*)d_in[6];
    const float* out_w = (const float*)d_in[7];
    const float* out_b = (const float*)d_in[8];
    // d_in[9] = h0 all-zeros, unused

    float* wmt = (float*)d_ws;   // 192*32*4 = 24576 B
    const int nrows = in_sizes[0] / IN;
    // R5 bug was here: waves/block is WPB=4, not 64. rpw = 32 for B=1M.
    const int rows_per_sweep = NB * WPB * 16;
    const int rpw = (nrows + rows_per_sweep - 1) / rows_per_sweep;

    prep_kernel<<<3 * HID, 32, 0, stream>>>(pre_w, pre_b, w_ih, b_ih, b_hh, wmt);
    gru_head_mfma<<<NB, 256, 0, stream>>>(x, wmt, b_hh, out_w, out_b,
                                          (float*)d_out, nrows, rpw);
}

// Round 7
// 102.755 us; speedup vs baseline: 2.1919x; 1.1437x over previous
//
#include <hip/hip_runtime.h>
#include <math.h>

// B=1048576, IN=25, H=64, OUT=6.  h0==0 => gh=b_hh; pre+ih fuse into W[192][26].
// R6 passed at 117.5us (MFMA formulation). R7: op-diet + latency hiding:
//  - single bf16 x path (xl split dropped; bias stays exact via W hi/lo cols)
//  - log2e prescaled into weights: r,z rows x(-log2e); n rows & b_hh_n x(2log2e);
//    ow,ob x(log2e) -> every exp2 loses its multiply, math unchanged
//  - v_cvt_pk_bf16_f32 for x->bf16 and h packing
//  - x prefetch (next iter's rows load under current iter's compute)
//  - __launch_bounds__(256,3): ~150 VGPR peak -> 3 waves/SIMD
// Layouts (verified by R6 pass): gate D[u][b]: col(b)=lane&15, row(u)=(lane>>4)*4+reg
// per 16-row tile t; head D[o][b] same; h C->B-frag via padded LDS bounce.

#define IN   25
#define HID  64
#define NOUT 6
#define LOG2E 1.4426950408889634f
#define NB   512   // blocks
#define WPB  4     // waves per block

typedef __attribute__((ext_vector_type(8))) short bf16x8_t;
typedef __attribute__((ext_vector_type(4))) float f32x4_t;

__device__ __forceinline__ float rcpf_(float x) { return __builtin_amdgcn_rcpf(x); }
__device__ __forceinline__ unsigned rne_bf16(float f) {
    unsigned u = __float_as_uint(f);
    u += 0x7fffu + ((u >> 16) & 1u);
    return u >> 16;
}
__device__ __forceinline__ float bf16_f(unsigned h) { return __uint_as_float(h << 16); }

// ---- prep: Wm[192][32] fp32, PRESCALED. cols 25/26 = bias hi/lo, 27..31 = 0.
__global__ void prep_kernel(const float* __restrict__ pre_w, const float* __restrict__ pre_b,
                            const float* __restrict__ w_ih, const float* __restrict__ b_ih,
                            const float* __restrict__ b_hh, float* __restrict__ wm) {
    int u = blockIdx.x;    // 0..191 (gate-unit, torch order r|z|n)
    int c = threadIdx.x;   // 0..31
    const float sc = (u < 2 * HID) ? -LOG2E : (2.0f * LOG2E);
    const float* wrow = w_ih + u * HID;
    float v = 0.0f;
    if (c < IN) {
        float s = 0.0f;
        for (int j = 0; j < HID; ++j) s = fmaf(wrow[j], pre_w[j * IN + c], s);
        v = s * sc;
    } else if (c == IN || c == IN + 1) {
        float s = 0.0f;
        for (int j = 0; j < HID; ++j) s = fmaf(wrow[j], pre_b[j], s);
        s += b_ih[u];
        if (u < 2 * HID) s += b_hh[u];     // r,z: h-bias folds in (h0==0)
        s *= sc;
        v = (c == IN) ? s : (s - bf16_f(rne_bf16(s)));
    }
    wm[u * 32 + c] = v;
}

__global__ __launch_bounds__(256, 3) void gru_head_mfma(const float* __restrict__ x,
                                                        const float* __restrict__ wm,
                                                        const float* __restrict__ b_hh,
                                                        const float* __restrict__ out_w,
                                                        const float* __restrict__ out_b,
                                                        float* __restrict__ out,
                                                        int nrows, int rpw) {
    __shared__ int4 lds4[4 * 144];         // 4 waves * 16 rows * 36 dwords (pad 36 vs 32)

    const int lane = threadIdx.x & 63;
    const int widx = threadIdx.x >> 6;
    const int b    = lane & 15;            // batch col in frags
    const int g4   = lane >> 4;            // k-group 0..3
    const int wave_g = blockIdx.x * WPB + widx;

    // ---- A-frags: W tiles (once). A[m=u_local][k=c]: m=lane&15, k=g4*8+j.
    bf16x8_t wf[12];
#pragma unroll
    for (int t = 0; t < 12; ++t) {
        const float* p = wm + (t * 16 + b) * 32 + g4 * 8;
        f32x4_t a = *(const f32x4_t*)p;
        f32x4_t c4 = *(const f32x4_t*)(p + 4);
        bf16x8_t f;
        f[0] = (short)rne_bf16(a.x); f[1] = (short)rne_bf16(a.y);
        f[2] = (short)rne_bf16(a.z); f[3] = (short)rne_bf16(a.w);
        f[4] = (short)rne_bf16(c4.x); f[5] = (short)rne_bf16(c4.y);
        f[6] = (short)rne_bf16(c4.z); f[7] = (short)rne_bf16(c4.w);
        wf[t] = f;
    }
    // ---- head A-frags: ow[o][k] * LOG2E, o=lane&15 (>=6 -> 0), k=g4*8+j+32s
    bf16x8_t owf[2];
#pragma unroll
    for (int s = 0; s < 2; ++s) {
        bf16x8_t f;
        if (b < NOUT) {
            const float* p = out_w + b * HID + 32 * s + g4 * 8;
#pragma unroll
            for (int j = 0; j < 8; ++j) f[j] = (short)rne_bf16(p[j] * LOG2E);
        } else {
#pragma unroll
            for (int j = 0; j < 8; ++j) f[j] = 0;
        }
        owf[s] = f;
    }
    // ---- bn' = 2*log2e*b_hh_n per-lane: u_h = 16*tt + 4*g4 + reg
    float bn_[4][4];
#pragma unroll
    for (int tt = 0; tt < 4; ++tt) {
        f32x4_t v = *(const f32x4_t*)(b_hh + 2 * HID + 16 * tt + 4 * g4);
        bn_[tt][0] = v.x * (2.0f * LOG2E); bn_[tt][1] = v.y * (2.0f * LOG2E);
        bn_[tt][2] = v.z * (2.0f * LOG2E); bn_[tt][3] = v.w * (2.0f * LOG2E);
    }
#pragma unroll
    for (int t = 0; t < 12; ++t) asm volatile("" : "+v"(wf[t]));
    asm volatile("" : "+v"(owf[0]), "+v"(owf[1]));
#pragma unroll
    for (int tt = 0; tt < 4; ++tt)
        asm volatile("" : "+v"(bn_[tt][0]), "+v"(bn_[tt][1]), "+v"(bn_[tt][2]), "+v"(bn_[tt][3]));

    const float ob0 = out_b[0] * LOG2E, ob1 = out_b[1] * LOG2E, ob2 = out_b[2] * LOG2E,
                ob3 = out_b[3] * LOG2E, ob4 = out_b[4] * LOG2E, ob5 = out_b[5] * LOG2E;
    const f32x4_t Z = {0.0f, 0.0f, 0.0f, 0.0f};

    int2* lds2 = (int2*)lds4;
    const int wb144 = widx * 144, wb288 = widx * 288;
    const int rowstart = wave_g * rpw * 16;

#define LOADX(DST, ITER) do {                                              \
        int rr_ = rowstart + (ITER) * 16 + b;                              \
        if (rr_ >= nrows) rr_ = nrows - 1;                                 \
        const float* xp_ = x + (size_t)rr_ * IN;                           \
        if (g4 < 3) {                                                      \
            __builtin_memcpy(&DST[0], xp_ + g4 * 8, 16);                   \
            __builtin_memcpy(&DST[4], xp_ + g4 * 8 + 4, 16);               \
        } else {                                                           \
            DST[0] = xp_[24]; DST[1] = 1.0f; DST[2] = 1.0f;                \
            DST[3] = DST[4] = DST[5] = DST[6] = DST[7] = 0.0f;             \
        }                                                                  \
    } while (0)

    float xnxt[8];
    LOADX(xnxt, 0);

#pragma unroll 1
    for (int it = 0; it < rpw; ++it) {
        const int rowbase = rowstart + it * 16;
        if (rowbase >= nrows) break;

        // ---- convert current x to bf16 B-frag (cvt_pk: dword = [bf16(s0)lo, bf16(s1)hi])
        union { unsigned u4[4]; bf16x8_t v; } xc;
        asm volatile("v_cvt_pk_bf16_f32 %0, %1, %2" : "=v"(xc.u4[0]) : "v"(xnxt[0]), "v"(xnxt[1]));
        asm volatile("v_cvt_pk_bf16_f32 %0, %1, %2" : "=v"(xc.u4[1]) : "v"(xnxt[2]), "v"(xnxt[3]));
        asm volatile("v_cvt_pk_bf16_f32 %0, %1, %2" : "=v"(xc.u4[2]) : "v"(xnxt[4]), "v"(xnxt[5]));
        asm volatile("v_cvt_pk_bf16_f32 %0, %1, %2" : "=v"(xc.u4[3]) : "v"(xnxt[6]), "v"(xnxt[7]));
        bf16x8_t xh8 = xc.v;

        // ---- prefetch next iter's x (lands during this iter's compute)
        if (it + 1 < rpw) LOADX(xnxt, it + 1);

        // ---- gate GEMM: 12 mfma (W prescaled; bias via k-slots 25/26)
        f32x4_t acc[12];
#pragma unroll
        for (int t = 0; t < 12; ++t)
            acc[t] = __builtin_amdgcn_mfma_f32_16x16x32_bf16(wf[t], xh8, Z, 0, 0, 0);

        // ---- activations (prescaled: no muls before exp2) + pack h + LDS bounce
#pragma unroll
        for (int tt = 0; tt < 4; ++tt) {
            float h[4];
#pragma unroll
            for (int reg = 0; reg < 4; ++reg) {
                float r = rcpf_(1.0f + exp2f(acc[tt][reg]));        // sig(ar)
                float z = rcpf_(1.0f + exp2f(acc[4 + tt][reg]));    // sig(az)
                float nv = fmaf(-2.0f,
                                rcpf_(exp2f(fmaf(r, bn_[tt][reg], acc[8 + tt][reg])) + 1.0f),
                                1.0f);                              // tanh(an + r*bn)
                h[reg] = fmaf(-z, nv, nv);                          // (1-z)*n
            }
            unsigned w0, w1;
            asm volatile("v_cvt_pk_bf16_f32 %0, %1, %2" : "=v"(w0) : "v"(h[0]), "v"(h[1]));
            asm volatile("v_cvt_pk_bf16_f32 %0, %1, %2" : "=v"(w1) : "v"(h[2]), "v"(h[3]));
            lds2[wb288 + b * 18 + 4 * tt + g4] = make_int2((int)w0, (int)w1);
        }
        asm volatile("s_waitcnt lgkmcnt(0)" ::: "memory");
        __builtin_amdgcn_sched_barrier(0);

        // ---- head: B-frag k = 32s + 8*g4 + j, col = b
        f32x4_t dD;
        {
            union { int4 i4; bf16x8_t h8; } u0, u1;
            int tt0 = (g4 >> 1);
            u0.i4 = lds4[wb144 + 9 * b + 2 * (0 + tt0) + (g4 & 1)];
            u1.i4 = lds4[wb144 + 9 * b + 2 * (2 + tt0) + (g4 & 1)];
            f32x4_t d = __builtin_amdgcn_mfma_f32_16x16x32_bf16(owf[0], u0.h8, Z, 0, 0, 0);
            dD = __builtin_amdgcn_mfma_f32_16x16x32_bf16(owf[1], u1.h8, d, 0, 0, 0);
        }

        // ---- softmax (logits already log2e-scaled): e = exp2(l - m)
        float lo4 = __uint_as_float((unsigned)__builtin_amdgcn_ds_swizzle(
                        (int)__float_as_uint(dD[0]), 0x401F));
        float lo5 = __uint_as_float((unsigned)__builtin_amdgcn_ds_swizzle(
                        (int)__float_as_uint(dD[1]), 0x401F));
        float l0 = dD[0] + ob0, l1 = dD[1] + ob1, l2 = dD[2] + ob2,
              l3 = dD[3] + ob3, l4 = lo4 + ob4, l5 = lo5 + ob5;
        float m = fmaxf(fmaxf(fmaxf(l0, l1), fmaxf(l2, l3)), fmaxf(l4, l5));
        float e0 = exp2f(l0 - m), e1 = exp2f(l1 - m), e2 = exp2f(l2 - m),
              e3 = exp2f(l3 - m), e4 = exp2f(l4 - m), e5 = exp2f(l5 - m);
        float is = rcpf_(e0 + e1 + e2 + e3 + e4 + e5);
        if (lane < 16 && rowbase + b < nrows) {
            float2* p2 = (float2*)(out + (size_t)(rowbase + b) * NOUT);
            p2[0] = make_float2(e0 * is, e1 * is);
            p2[1] = make_float2(e2 * is, e3 * is);
            p2[2] = make_float2(e4 * is, e5 * is);
        }
    }
#undef LOADX
}

extern "C" void kernel_launch(void* const* d_in, const int* in_sizes, int n_in,
                              void* d_out, int out_size, void* d_ws, size_t ws_size,
                              hipStream_t stream) {
    const float* x     = (const float*)d_in[0];
    const float* pre_w = (const float*)d_in[1];
    const float* pre_b = (const float*)d_in[2];
    const float* w_ih  = (const float*)d_in[3];
    // d_in[4] = w_hh unused (h0==0 -> gh=b_hh exactly)
    const float* b_ih  = (const float*)d_in[5];
    const float* b_hh  = (const float*)d_in[6];
    const float* out_w = (const float*)d_in[7];
    const float* out_b = (const float*)d_in[8];
    // d_in[9] = h0 all-zeros, unused

    float* wmt = (float*)d_ws;   // 192*32*4 = 24576 B
    const int nrows = in_sizes[0] / IN;
    const int rows_per_sweep = NB * WPB * 16;
    const int rpw = (nrows + rows_per_sweep - 1) / rows_per_sweep;   // 32 for B=1M

    prep_kernel<<<3 * HID, 32, 0, stream>>>(pre_w, pre_b, w_ih, b_ih, b_hh, wmt);
    gru_head_mfma<<<NB, 256, 0, stream>>>(x, wmt, b_hh, out_w, out_b,
                                          (float*)d_out, nrows, rpw);
}

// Round 9
// 72.606 us; speedup vs baseline: 3.1021x; 1.4152x over previous
//
#include <hip/hip_runtime.h>

// B=1048576, IN=25, H=64, OUT=6.  h0==0 => gh=b_hh; pre+ih fuse into W[192][26].
// R6 MFMA: 117.5us. R7 op-diet: 102.8us. R8 FAILED (absmax 1.95e-2):
// inline-asm v_exp_f32 hides the VALU-TRANS->consumer hazard from LLVM's
// hazard recognizer (no s_nop inserted after an opaque asm) -> stale-register
// reads of the exp result. R9: __builtin_amdgcn_exp2f (same raw v_exp_f32,
// compiler-known trans op, hazards handled) + reinstated explicit
// s_waitcnt lgkmcnt(0)+sched_barrier before the LDS read-back (R7-proven).
// Keeps R8's NB=768 interleaved-tile grid (fills 3 waves/SIMD residency).
// Layouts (R6-verified): gate D[u][b]: col(b)=lane&15, row(u)=(lane>>4)*4+reg,
// tile t -> units t*16..t*16+15; head same; h C->B-frag via padded LDS bounce.

#define IN   25
#define HID  64
#define NOUT 6
#define LOG2E 1.4426950408889634f
#define NB   768   // blocks = 3 blocks/CU residency
#define WPB  4     // waves per block

typedef __attribute__((ext_vector_type(8))) short bf16x8_t;
typedef __attribute__((ext_vector_type(4))) float f32x4_t;

__device__ __forceinline__ float rcpf_(float x) { return __builtin_amdgcn_rcpf(x); }
__device__ __forceinline__ float exp2_(float a) { return __builtin_amdgcn_exp2f(a); }
__device__ __forceinline__ unsigned rne_bf16(float f) {
    unsigned u = __float_as_uint(f);
    u += 0x7fffu + ((u >> 16) & 1u);
    return u >> 16;
}
__device__ __forceinline__ float bf16_f(unsigned h) { return __uint_as_float(h << 16); }

// ---- prep: Wm[192][32] fp32, PRESCALED. cols 25/26 = bias hi/lo, 27..31 = 0.
__global__ void prep_kernel(const float* __restrict__ pre_w, const float* __restrict__ pre_b,
                            const float* __restrict__ w_ih, const float* __restrict__ b_ih,
                            const float* __restrict__ b_hh, float* __restrict__ wm) {
    int u = blockIdx.x;    // 0..191 (gate-unit, torch order r|z|n)
    int c = threadIdx.x;   // 0..31
    const float sc = (u < 2 * HID) ? -LOG2E : (2.0f * LOG2E);
    const float* wrow = w_ih + u * HID;
    float v = 0.0f;
    if (c < IN) {
        float s = 0.0f;
        for (int j = 0; j < HID; ++j) s = fmaf(wrow[j], pre_w[j * IN + c], s);
        v = s * sc;
    } else if (c == IN || c == IN + 1) {
        float s = 0.0f;
        for (int j = 0; j < HID; ++j) s = fmaf(wrow[j], pre_b[j], s);
        s += b_ih[u];
        if (u < 2 * HID) s += b_hh[u];     // r,z: h-bias folds in (h0==0)
        s *= sc;
        v = (c == IN) ? s : (s - bf16_f(rne_bf16(s)));
    }
    wm[u * 32 + c] = v;
}

__global__ __launch_bounds__(256, 3) void gru_head_mfma(const float* __restrict__ x,
                                                        const float* __restrict__ wm,
                                                        const float* __restrict__ b_hh,
                                                        const float* __restrict__ out_w,
                                                        const float* __restrict__ out_b,
                                                        float* __restrict__ out,
                                                        int nrows) {
    __shared__ int4 lds4[4 * 144];         // 4 waves * 16 rows * 36 dwords (pad 36 vs 32)

    const int lane = threadIdx.x & 63;
    const int widx = threadIdx.x >> 6;
    const int b    = lane & 15;            // batch col in frags
    const int g4   = lane >> 4;            // k-group 0..3
    const int wave_g = blockIdx.x * WPB + widx;
    const int NW   = NB * WPB;             // total waves (interleaved tile stride)

    // ---- A-frags: W tiles (once). A[m=u_local][k=c]: m=lane&15, k=g4*8+j.
    bf16x8_t wf[12];
#pragma unroll
    for (int t = 0; t < 12; ++t) {
        const float* p = wm + (t * 16 + b) * 32 + g4 * 8;
        f32x4_t a = *(const f32x4_t*)p;
        f32x4_t c4 = *(const f32x4_t*)(p + 4);
        bf16x8_t f;
        f[0] = (short)rne_bf16(a.x); f[1] = (short)rne_bf16(a.y);
        f[2] = (short)rne_bf16(a.z); f[3] = (short)rne_bf16(a.w);
        f[4] = (short)rne_bf16(c4.x); f[5] = (short)rne_bf16(c4.y);
        f[6] = (short)rne_bf16(c4.z); f[7] = (short)rne_bf16(c4.w);
        wf[t] = f;
    }
    // ---- head A-frags: ow[o][k] * LOG2E, o=lane&15 (>=6 -> 0), k=g4*8+j+32s
    bf16x8_t owf[2];
#pragma unroll
    for (int s = 0; s < 2; ++s) {
        bf16x8_t f;
        if (b < NOUT) {
            const float* p = out_w + b * HID + 32 * s + g4 * 8;
#pragma unroll
            for (int j = 0; j < 8; ++j) f[j] = (short)rne_bf16(p[j] * LOG2E);
        } else {
#pragma unroll
            for (int j = 0; j < 8; ++j) f[j] = 0;
        }
        owf[s] = f;
    }
    // ---- bn' = 2*log2e*b_hh_n per-lane: u_h = 16*tt + 4*g4 + reg
    float bn_[4][4];
#pragma unroll
    for (int tt = 0; tt < 4; ++tt) {
        f32x4_t v = *(const f32x4_t*)(b_hh + 2 * HID + 16 * tt + 4 * g4);
        bn_[tt][0] = v.x * (2.0f * LOG2E); bn_[tt][1] = v.y * (2.0f * LOG2E);
        bn_[tt][2] = v.z * (2.0f * LOG2E); bn_[tt][3] = v.w * (2.0f * LOG2E);
    }
#pragma unroll
    for (int t = 0; t < 12; ++t) asm volatile("" : "+v"(wf[t]));
    asm volatile("" : "+v"(owf[0]), "+v"(owf[1]));
#pragma unroll
    for (int tt = 0; tt < 4; ++tt)
        asm volatile("" : "+v"(bn_[tt][0]), "+v"(bn_[tt][1]), "+v"(bn_[tt][2]), "+v"(bn_[tt][3]));

    const float ob0 = out_b[0] * LOG2E, ob1 = out_b[1] * LOG2E, ob2 = out_b[2] * LOG2E,
                ob3 = out_b[3] * LOG2E, ob4 = out_b[4] * LOG2E, ob5 = out_b[5] * LOG2E;
    const f32x4_t Z = {0.0f, 0.0f, 0.0f, 0.0f};

    int2* lds2 = (int2*)lds4;
    const int wb144 = widx * 144, wb288 = widx * 288;
    const int ntiles = (nrows + 15) >> 4;

#define LOADX(DST, TILE) do {                                              \
        int rr_ = (TILE) * 16 + b;                                         \
        if (rr_ >= nrows) rr_ = nrows - 1;                                 \
        const float* xp_ = x + (size_t)rr_ * IN;                           \
        if (g4 < 3) {                                                      \
            __builtin_memcpy(&DST[0], xp_ + g4 * 8, 16);                   \
            __builtin_memcpy(&DST[4], xp_ + g4 * 8 + 4, 16);               \
        } else {                                                           \
            DST[0] = xp_[24]; DST[1] = 1.0f; DST[2] = 1.0f;                \
            DST[3] = DST[4] = DST[5] = DST[6] = DST[7] = 0.0f;             \
        }                                                                  \
    } while (0)

    float xnxt[8];
    int tile = wave_g;
    if (tile < ntiles) LOADX(xnxt, tile);

#pragma unroll 1
    while (tile < ntiles) {
        const int rowbase = tile * 16;

        // ---- current x -> bf16 B-frag (cvt_pk: dword = [bf16(s0)lo, bf16(s1)hi])
        union { unsigned u4[4]; bf16x8_t v; } xc;
        asm("v_cvt_pk_bf16_f32 %0, %1, %2" : "=v"(xc.u4[0]) : "v"(xnxt[0]), "v"(xnxt[1]));
        asm("v_cvt_pk_bf16_f32 %0, %1, %2" : "=v"(xc.u4[1]) : "v"(xnxt[2]), "v"(xnxt[3]));
        asm("v_cvt_pk_bf16_f32 %0, %1, %2" : "=v"(xc.u4[2]) : "v"(xnxt[4]), "v"(xnxt[5]));
        asm("v_cvt_pk_bf16_f32 %0, %1, %2" : "=v"(xc.u4[3]) : "v"(xnxt[6]), "v"(xnxt[7]));
        bf16x8_t xh8 = xc.v;

        // ---- prefetch next tile's x (lands under this tile's compute)
        const int nxt = tile + NW;
        if (nxt < ntiles) LOADX(xnxt, nxt);

        // ---- gate GEMM: 12 mfma (W prescaled; bias via k-slots 25/26)
        f32x4_t acc[12];
#pragma unroll
        for (int t = 0; t < 12; ++t)
            acc[t] = __builtin_amdgcn_mfma_f32_16x16x32_bf16(wf[t], xh8, Z, 0, 0, 0);

        // ---- activations (builtin raw v_exp, prescaled args) + pack h + LDS bounce
#pragma unroll
        for (int tt = 0; tt < 4; ++tt) {
            float h[4];
#pragma unroll
            for (int reg = 0; reg < 4; ++reg) {
                float r = rcpf_(1.0f + exp2_(acc[tt][reg]));        // sig(ar)
                float z = rcpf_(1.0f + exp2_(acc[4 + tt][reg]));    // sig(az)
                float nv = fmaf(-2.0f,
                                rcpf_(exp2_(fmaf(r, bn_[tt][reg], acc[8 + tt][reg])) + 1.0f),
                                1.0f);                              // tanh(an + r*bn)
                h[reg] = fmaf(-z, nv, nv);                          // (1-z)*n
            }
            unsigned w0, w1;
            asm("v_cvt_pk_bf16_f32 %0, %1, %2" : "=v"(w0) : "v"(h[0]), "v"(h[1]));
            asm("v_cvt_pk_bf16_f32 %0, %1, %2" : "=v"(w1) : "v"(h[2]), "v"(h[3]));
            lds2[wb288 + b * 18 + 4 * tt + g4] = make_int2((int)w0, (int)w1);
        }
        asm volatile("s_waitcnt lgkmcnt(0)" ::: "memory");
        __builtin_amdgcn_sched_barrier(0);

        // ---- head: B-frag k = 32s + 8*g4 + j, col = b
        f32x4_t dD;
        {
            union { int4 i4; bf16x8_t h8; } u0, u1;
            int tt0 = (g4 >> 1);
            u0.i4 = lds4[wb144 + 9 * b + 2 * (0 + tt0) + (g4 & 1)];
            u1.i4 = lds4[wb144 + 9 * b + 2 * (2 + tt0) + (g4 & 1)];
            f32x4_t d = __builtin_amdgcn_mfma_f32_16x16x32_bf16(owf[0], u0.h8, Z, 0, 0, 0);
            dD = __builtin_amdgcn_mfma_f32_16x16x32_bf16(owf[1], u1.h8, d, 0, 0, 0);
        }

        // ---- softmax (logits already log2e-scaled): e = exp2(l - m)
        float lo4 = __uint_as_float((unsigned)__builtin_amdgcn_ds_swizzle(
                        (int)__float_as_uint(dD[0]), 0x401F));
        float lo5 = __uint_as_float((unsigned)__builtin_amdgcn_ds_swizzle(
                        (int)__float_as_uint(dD[1]), 0x401F));
        float l0 = dD[0] + ob0, l1 = dD[1] + ob1, l2 = dD[2] + ob2,
              l3 = dD[3] + ob3, l4 = lo4 + ob4, l5 = lo5 + ob5;
        float m = fmaxf(fmaxf(fmaxf(l0, l1), fmaxf(l2, l3)), fmaxf(l4, l5));
        float e0 = exp2_(l0 - m), e1 = exp2_(l1 - m), e2 = exp2_(l2 - m),
              e3 = exp2_(l3 - m), e4 = exp2_(l4 - m), e5 = exp2_(l5 - m);
        float is = rcpf_(e0 + e1 + e2 + e3 + e4 + e5);
        if (lane < 16 && rowbase + b < nrows) {
            float2* p2 = (float2*)(out + (size_t)(rowbase + b) * NOUT);
            p2[0] = make_float2(e0 * is, e1 * is);
            p2[1] = make_float2(e2 * is, e3 * is);
            p2[2] = make_float2(e4 * is, e5 * is);
        }
        tile = nxt;
    }
#undef LOADX
}

extern "C" void kernel_launch(void* const* d_in, const int* in_sizes, int n_in,
                              void* d_out, int out_size, void* d_ws, size_t ws_size,
                              hipStream_t stream) {
    const float* x     = (const float*)d_in[0];
    const float* pre_w = (const float*)d_in[1];
    const float* pre_b = (const float*)d_in[2];
    const float* w_ih  = (const float*)d_in[3];
    // d_in[4] = w_hh unused (h0==0 -> gh=b_hh exactly)
    const float* b_ih  = (const float*)d_in[5];
    const float* b_hh  = (const float*)d_in[6];
    const float* out_w = (const float*)d_in[7];
    const float* out_b = (const float*)d_in[8];
    // d_in[9] = h0 all-zeros, unused

    float* wmt = (float*)d_ws;   // 192*32*4 = 24576 B
    const int nrows = in_sizes[0] / IN;

    prep_kernel<<<3 * HID, 32, 0, stream>>>(pre_w, pre_b, w_ih, b_ih, b_hh, wmt);
    gru_head_mfma<<<NB, 256, 0, stream>>>(x, wmt, b_hh, out_w, out_b,
                                          (float*)d_out, nrows);
}